// Round 4
// baseline (12675.581 us; speedup 1.0000x reference)
//
#include <hip/hip_runtime.h>

#define ALPHA 0.9f
#define THRESH 1.0f
#define BATCH 512
#define CIN 16
#define TSTEPS 2000
#define NRES 1024
#define NCLS 10

#define NGROUP 32       // 32 batch groups of 16 rows
#define NPAIR 16        // block = (pair j, slice bl4): two teams, groups 2j / 2j+1
#define NSLICE 16       // 16 slices x 64 neurons

typedef int   v4i __attribute__((ext_vector_type(4)));
typedef float v4f __attribute__((ext_vector_type(4)));
typedef short v8s __attribute__((ext_vector_type(8)));

// ---- ws layout (bytes) ---- (identical to the verified 5.14 ms kernel)
#define SLOTC_OFF  8192     // max|W_clf| bits
#define ROWMAX_OFF 9216     // per-row max|W_res[n][:]|, 1024 floats
#define MASK_OFF   16384    // tagged masks: 2 par x 32 g x 16 b x 64 prod x 4 B = 256 KB
#define WQF_OFF    278528   // W_res int8, MFMA-fragment order: 1 MB
#define WCF_OFF    1327104  // W_clf int8 fragment tile: 16 KB

// LDS: B slice 64KB + 2 x A(16x1040) + 2 x xA(1KB) + 2 x redC(4KB) + barCtr
#define LDS_A_OFF   65536
#define LDS_XA_OFF  98816
#define LDS_RC_OFF  100864
#define LDS_BAR_OFF 109056
#define LDS_BYTES   109072

__global__ __launch_bounds__(256) void maxabs_kernel(const float* __restrict__ W,
                                                     int n, unsigned* __restrict__ slot) {
    unsigned m = 0u;
    for (int i = blockIdx.x * 256 + threadIdx.x; i < n; i += gridDim.x * 256)
        m = max(m, __float_as_uint(W[i]) & 0x7fffffffu);
#pragma unroll
    for (int off = 32; off >= 1; off >>= 1)
        m = max(m, (unsigned)__shfl_xor((int)m, off, 64));
    if ((threadIdx.x & 63) == 0) atomicMax(slot, m);
}

// per-row max|W_res[n][:]| — one wave per row, plain store (deterministic)
__global__ __launch_bounds__(256) void rowmax_kernel(const float* __restrict__ W,
                                                     float* __restrict__ rowmax) {
    const int row = blockIdx.x * 4 + ((int)threadIdx.x >> 6);
    const int lane = threadIdx.x & 63;
    float m = 0.f;
    for (int j = lane; j < NRES; j += 64) m = fmaxf(m, fabsf(W[row * NRES + j]));
#pragma unroll
    for (int off = 32; off >= 1; off >>= 1) m = fmaxf(m, __shfl_xor(m, off, 64));
    if (lane == 0) rowmax[row] = m;
}

// W_res -> signed-int8 (PER-ROW scale) in MFMA B-fragment order (unchanged):
// 16-neuron chunk c = n>>4 owns 16 KB tile at c*16384.
__global__ __launch_bounds__(256) void quant_res(const float* __restrict__ W,
                                                 const float* __restrict__ rowmax,
                                                 unsigned* __restrict__ dst) {
    const int o4 = blockIdx.x * 256 + threadIdx.x;
    const int bl = o4 >> 15, wv = (o4 >> 12) & 7, kt = (o4 >> 8) & 15;
    const int L = (o4 >> 2) & 63, i0 = (o4 & 3) * 4;
    const int n = bl * 128 + wv * 16 + (L & 15);
    const int k = kt * 64 + (L >> 4) * 16 + i0;
    const float inv = 127.0f / rowmax[n];
    unsigned dw = 0;
#pragma unroll
    for (int j = 0; j < 4; ++j) {
        float q = rintf(W[n * NRES + k + j] * inv);
        q = fminf(fmaxf(q, -127.f), 127.f);
        dw |= ((unsigned)((int)q & 0xff)) << (8 * j);
    }
    dst[o4] = dw;
}

// W_clf -> int8 fragment tile (16 cols, cls>=10 zero): 4096 dwords
__global__ __launch_bounds__(256) void quant_clf(const float* __restrict__ W,
                                                 const unsigned* __restrict__ slot,
                                                 unsigned* __restrict__ dst) {
    const int o4 = blockIdx.x * 256 + threadIdx.x;
    const int kt = (o4 >> 8) & 15, L = (o4 >> 2) & 63, i0 = (o4 & 3) * 4;
    const int cls = L & 15;
    const int k = kt * 64 + (L >> 4) * 16 + i0;
    const float inv = 127.0f / __uint_as_float(*slot);
    unsigned dw = 0;
    if (cls < NCLS) {
#pragma unroll
        for (int j = 0; j < 4; ++j) {
            float q = rintf(W[cls * NRES + k + j] * inv);
            q = fminf(fmaxf(q, -127.f), 127.f);
            dw |= ((unsigned)((int)q & 0xff)) << (8 * j);
        }
    }
    dst[o4] = dw;
}

__device__ __forceinline__ unsigned short f2bf(float f) {
    unsigned u = __float_as_uint(f);
    return (unsigned short)((u + 0x7fffu + ((u >> 16) & 1u)) >> 16);
}

// Poll 16 B (4 tagged dwords) with one agent-visible dwordx4. Per-dword
// atomicity is what matters: each dword is published atomically and carries
// its own tag, so a torn 16B read just fails the tag check and retries.
__device__ __forceinline__ v4i poll16(const v4i* mp, unsigned want) {
    v4i u;
    for (;;) {
        asm volatile("global_load_dwordx4 %0, %1, off sc0 sc1\n\ts_waitcnt vmcnt(0)"
                     : "=v"(u) : "v"(mp) : "memory");
        if ((((unsigned)u[0] >> 16) == want) & (((unsigned)u[1] >> 16) == want) &
            (((unsigned)u[2] >> 16) == want) & (((unsigned)u[3] >> 16) == want)) break;
        __builtin_amdgcn_s_sleep(1);
    }
    return u;
}

// 32 spike bits -> 32 int8 {0,1} bytes (carry-free nibble spread)
__device__ __forceinline__ void expand32(unsigned m, char* dst) {
    unsigned w[8];
#pragma unroll
    for (int d = 0; d < 8; ++d)
        w[d] = (((m >> (4 * d)) & 15u) * 0x00204081u) & 0x01010101u;
    *(v4i*)dst = *(v4i*)&w[0];
    *(v4i*)(dst + 16) = *(v4i*)&w[4];
}

// Per-team soft barrier: monotonic LDS counter, one ds_add per wave.
// lgkmcnt(0) before signaling orders all prior LDS writes; compiler fences
// (memory clobber + sched_barrier) stop hoisting/sinking across it.
__device__ __forceinline__ void team_bar(unsigned* ctr, int L, unsigned tgt) {
    asm volatile("s_waitcnt lgkmcnt(0)" ::: "memory");
    __builtin_amdgcn_sched_barrier(0);
    if (L == 0)
        __hip_atomic_fetch_add(ctr, 1u, __ATOMIC_RELAXED, __HIP_MEMORY_SCOPE_WORKGROUP);
    while (__hip_atomic_load(ctr, __ATOMIC_RELAXED, __HIP_MEMORY_SCOPE_WORKGROUP) < tgt) {}
    asm volatile("" ::: "memory");
    __builtin_amdgcn_sched_barrier(0);
}

// ---------------------------------------------------------------------------
// TWO-TEAM TLP: 256 blocks x 512 threads (1/CU). Block = (pair j=q&15, slice
// bl4=q>>4). Waves 0-3 = team 0 (group 2j), waves 4-7 = team 1 (group 2j+1);
// both teams cover the SAME 64 neurons (shared 64 KB int8 W slice in LDS).
// Each SIMD hosts one wave from EACH team, so a team's publish->poll stall is
// hidden under the other team's MFMA/VALU work. Teams sync only via per-team
// LDS soft barriers — no block-wide __syncthreads in the loop. Mask format,
// quantization, MFMA order: bit-identical to the verified 5.14 ms kernel
// (producer dword index = n>>4 is unchanged by the 128->64 slice split).
// ---------------------------------------------------------------------------
__global__ __launch_bounds__(512, 1) void reservoir_mfma(
    const float* __restrict__ x, const float* __restrict__ W_in,
    unsigned char* __restrict__ ws, float* __restrict__ out)
{
    const int q    = (int)blockIdx.x;
    const int j    = q & 15;        // pair: 16 blocks of pair j share q%8 (XCD heuristic)
    const int bl4  = q >> 4;        // slice 0..15 (64 neurons)
    const int tid  = (int)threadIdx.x;
    const int T    = tid >> 8;      // team 0/1
    const int tt   = tid & 255;     // thread-in-team
    const int wvt  = tt >> 6;       // team wave 0..3
    const int L    = tt & 63;
    const int col  = L & 15;        // MFMA n-col (neuron/cls)
    const int rowq = L >> 4;        // batch quad
    const int g    = 2 * j + T;     // my team's batch group

    extern __shared__ char lds[];
    char* B_lds = lds;                                        // 64 KB shared slice
    char* A_t   = lds + LDS_A_OFF + T * 16640;                // 16 x 1040 per team
    unsigned short* xA_t = (unsigned short*)(lds + LDS_XA_OFF + T * 1024);
    char* redC_t = lds + LDS_RC_OFF + T * 4096;               // 4 waves x 1 KB
    unsigned* barCtr = (unsigned*)(lds + LDS_BAR_OFF);
    unsigned* ctr = barCtr + T;

    const float* rowmax = (const float*)(ws + ROWMAX_OFF);
    const float cscale = __uint_as_float(*(const unsigned*)(ws + SLOTC_OFF)) * (1.0f / 127.0f);
    unsigned char* maskbuf = ws + MASK_OFF;
    const unsigned char* wqf = ws + WQF_OFF;
    const unsigned char* wcf = ws + WCF_OFF;

    const int nn = bl4 * 64 + wvt * 16 + col;               // my output neuron
    const float dscale = rowmax[nn] * (1.0f / 127.0f);
    const bool clfBlk = (bl4 == 0);

    if (tid < 2) barCtr[tid] = 0;

    // ---- load the shared 64 KB weight slice (chunks 4*bl4..4*bl4+3)
    {
        const v4i* src = (const v4i*)(wqf + (size_t)bl4 * 65536);
        v4i* dst = (v4i*)B_lds;
        for (int i = tid; i < 4096; i += 512) dst[i] = src[i];
    }

    // ---- W_in hi/lo bf16 B-fragments
    v8s binf_h, binf_l;
#pragma unroll
    for (int i = 0; i < 8; ++i) {
        const int c = (rowq * 8 + i) & 15;
        const float w = W_in[nn * CIN + c];
        const unsigned short h = f2bf(w);
        const float wl = w - __uint_as_float((unsigned)h << 16);
        binf_h[i] = (short)h;
        binf_l[i] = (short)f2bf(wl);
    }

    // ---- classifier fragments (clf blocks: team wave wvt owns kt=4wvt..4wvt+3)
    v4i bcf0 = {0,0,0,0}, bcf1 = {0,0,0,0}, bcf2 = {0,0,0,0}, bcf3 = {0,0,0,0};
    if (clfBlk) {
        bcf0 = *(const v4i*)(wcf + (4 * wvt + 0) * 1024 + L * 16);
        bcf1 = *(const v4i*)(wcf + (4 * wvt + 1) * 1024 + L * 16);
        bcf2 = *(const v4i*)(wcf + (4 * wvt + 2) * 1024 + L * 16);
        bcf3 = *(const v4i*)(wcf + (4 * wvt + 3) * 1024 + L * 16);
    }

    float v[4]  = {0.f, 0.f, 0.f, 0.f};
    int   accv[4] = {0, 0, 0, 0};
    float vc[4] = {0.f, 0.f, 0.f, 0.f};   // live on clf teams, wave 0
    int   accc[4] = {0, 0, 0, 0};

    // mask poll: thread (mb,ms2) polls 16B = 4 producer dwords of row mb
    const int mb = tt >> 4, ms2 = tt & 15;
    const v4i* mp0 = (const v4i*)(maskbuf +
        (size_t)((0 * NGROUP + g) * 16 + mb) * 256 + ms2 * 16);
    const v4i* mp1 = (const v4i*)(maskbuf +
        (size_t)((1 * NGROUP + g) * 16 + mb) * 256 + ms2 * 16);

    // x staging: 256 team threads = 16 rows x 16 cin
    const int xb = tt >> 4, xc = tt & 15;
    const size_t xoff = ((size_t)(g * 16 + xb) * CIN + xc) * TSTEPS;

    __syncthreads();   // B_lds + barCtr ready (pre-loop, block-wide: safe)

    unsigned bt = 0;   // team-barrier target (increments of 4 waves)

    for (int t = 0; t < TSTEPS; ++t) {
        // x_t load issued before the poll
        float xval = x[xoff + t];

        if (t > 0) {
            // ---- poll tagged masks of step t-1 (parity (t-1)&1), expand to A
            const v4i u = poll16(((t - 1) & 1) ? mp1 : mp0, (unsigned)t);
            const unsigned m0 = ((unsigned)u[0] & 0xffffu) | (((unsigned)u[1] & 0xffffu) << 16);
            const unsigned m1 = ((unsigned)u[2] & 0xffffu) | (((unsigned)u[3] & 0xffffu) << 16);
            char* dst = A_t + mb * 1040 + ms2 * 64;
            expand32(m0, dst);
            expand32(m1, dst + 32);
        }
        // ---- stage x_t hi/lo
        {
            const unsigned short h = f2bf(xval);
            const float lo2 = xval - __uint_as_float((unsigned)h << 16);
            xA_t[xb * 32 + xc] = h;
            xA_t[xb * 32 + 16 + xc] = f2bf(lo2);
        }
        bt += 4; team_bar(ctr, L, bt);   // S2: A + xA ready (team-local)

        // ---- input projection: (xh+xl).(Wh+Wl), 2 chained bf16 MFMAs
        v4f Din;
        {
            const v8s xa = *(const v8s*)((const char*)xA_t + col * 64 + rowq * 16);
            v4f z = {0.f, 0.f, 0.f, 0.f};
            const v4f D1 = __builtin_amdgcn_mfma_f32_16x16x32_bf16(xa, binf_h, z, 0, 0, 0);
            Din = __builtin_amdgcn_mfma_f32_16x16x32_bf16(xa, binf_l, D1, 0, 0, 0);
        }

        // ---- recurrent: 16 x mfma_i32_16x16x64_i8, 2 independent chains (exact)
        v4i Drec = {0, 0, 0, 0};
        if (t > 0) {
            const char* Bb = B_lds + wvt * 16384;
            const char* Ab = A_t + col * 1040 + rowq * 16;
            v4i Dr0 = {0,0,0,0}, Dr1 = {0,0,0,0};
#pragma unroll 4
            for (int kt = 0; kt < 16; kt += 2) {
                const v4i a0 = *(const v4i*)(Ab + kt * 64);
                const v4i b0 = *(const v4i*)(Bb + kt * 1024 + L * 16);
                const v4i a1 = *(const v4i*)(Ab + (kt + 1) * 64);
                const v4i b1 = *(const v4i*)(Bb + (kt + 1) * 1024 + L * 16);
                Dr0 = __builtin_amdgcn_mfma_i32_16x16x64_i8(a0, b0, Dr0, 0, 0, 0);
                Dr1 = __builtin_amdgcn_mfma_i32_16x16x64_i8(a1, b1, Dr1, 0, 0, 0);
            }
#pragma unroll
            for (int r = 0; r < 4; ++r) Drec[r] = Dr0[r] + Dr1[r];
        }

        // ---- LIF + spikes + ballots + EARLY publish (before S3: shortens the
        //      producer->consumer chain; writes only registers/global)
        unsigned long long bal0, bal1, bal2, bal3;
        {
            float vn; int s;
            vn = ALPHA * v[0] + Din[0] + dscale * (float)Drec[0];
            s = (vn >= THRESH); accv[0] += s; v[0] = s ? 0.f : vn; bal0 = __ballot(s);
            vn = ALPHA * v[1] + Din[1] + dscale * (float)Drec[1];
            s = (vn >= THRESH); accv[1] += s; v[1] = s ? 0.f : vn; bal1 = __ballot(s);
            vn = ALPHA * v[2] + Din[2] + dscale * (float)Drec[2];
            s = (vn >= THRESH); accv[2] += s; v[2] = s ? 0.f : vn; bal2 = __ballot(s);
            vn = ALPHA * v[3] + Din[3] + dscale * (float)Drec[3];
            s = (vn >= THRESH); accv[3] += s; v[3] = s ? 0.f : vn; bal3 = __ballot(s);
        }
        {
            const int p = t & 1;
            if (L < 16) {
                const int b = L;
                const unsigned long long bb = (b & 2) ? ((b & 1) ? bal3 : bal2)
                                                      : ((b & 1) ? bal1 : bal0);
                const unsigned fld = (unsigned)((bb >> ((b >> 2) * 16)) & 0xFFFFu);
                unsigned* mp = (unsigned*)(maskbuf +
                    (size_t)((p * NGROUP + g) * 16 + b) * 256 + (bl4 * 4 + wvt) * 4);
                __hip_atomic_store(mp, ((unsigned)(t + 1) << 16) | fld,
                                   __ATOMIC_RELAXED, __HIP_MEMORY_SCOPE_AGENT);
            }
        }

        // ---- classifier partials (clf blocks: team wave wvt does kt=4wvt..+3)
        if (clfBlk && t > 0) {
            const char* Ab = A_t + col * 1040 + rowq * 16;
            v4i Dc = {0, 0, 0, 0};
            Dc = __builtin_amdgcn_mfma_i32_16x16x64_i8(
                     *(const v4i*)(Ab + (4 * wvt + 0) * 64), bcf0, Dc, 0, 0, 0);
            Dc = __builtin_amdgcn_mfma_i32_16x16x64_i8(
                     *(const v4i*)(Ab + (4 * wvt + 1) * 64), bcf1, Dc, 0, 0, 0);
            Dc = __builtin_amdgcn_mfma_i32_16x16x64_i8(
                     *(const v4i*)(Ab + (4 * wvt + 2) * 64), bcf2, Dc, 0, 0, 0);
            Dc = __builtin_amdgcn_mfma_i32_16x16x64_i8(
                     *(const v4i*)(Ab + (4 * wvt + 3) * 64), bcf3, Dc, 0, 0, 0);
            *(v4i*)(redC_t + wvt * 1024 + L * 16) = Dc;
        }
        bt += 4; team_bar(ctr, L, bt);   // S3: A/xA consumed; redC ready

        // ---- classifier reduce + LIF (clf teams, wave 0; reads redC after S3)
        if (clfBlk && wvt == 0 && t > 0) {
            v4i c0 = *(const v4i*)(redC_t + 0 * 1024 + L * 16);
#pragma unroll
            for (int jj = 1; jj < 4; ++jj) {
                const v4i cj = *(const v4i*)(redC_t + jj * 1024 + L * 16);
#pragma unroll
                for (int r = 0; r < 4; ++r) c0[r] += cj[r];
            }
#pragma unroll
            for (int r = 0; r < 4; ++r) {
                const float vcn = ALPHA * vc[r] + cscale * (float)c0[r];
                const int sc = (vcn >= THRESH);
                accc[r] += sc;
                vc[r] = sc ? 0.f : vcn;
            }
        }
        // next-step A-writes are gated by each thread's own poll + S3 passage
    }

    // ---- epilogue: classifier flush with s_{T-1} (parity 1, tag TSTEPS)
    if (clfBlk) {
        {
            const v4i u = poll16(mp1, (unsigned)TSTEPS);
            const unsigned m0 = ((unsigned)u[0] & 0xffffu) | (((unsigned)u[1] & 0xffffu) << 16);
            const unsigned m1 = ((unsigned)u[2] & 0xffffu) | (((unsigned)u[3] & 0xffffu) << 16);
            char* dst = A_t + mb * 1040 + ms2 * 64;
            expand32(m0, dst);
            expand32(m1, dst + 32);
        }
        __syncthreads();   // block-wide OK: all 512 threads of clf blocks are here
        {
            const char* Ab = A_t + col * 1040 + rowq * 16;
            v4i Dc = {0, 0, 0, 0};
            Dc = __builtin_amdgcn_mfma_i32_16x16x64_i8(
                     *(const v4i*)(Ab + (4 * wvt + 0) * 64), bcf0, Dc, 0, 0, 0);
            Dc = __builtin_amdgcn_mfma_i32_16x16x64_i8(
                     *(const v4i*)(Ab + (4 * wvt + 1) * 64), bcf1, Dc, 0, 0, 0);
            Dc = __builtin_amdgcn_mfma_i32_16x16x64_i8(
                     *(const v4i*)(Ab + (4 * wvt + 2) * 64), bcf2, Dc, 0, 0, 0);
            Dc = __builtin_amdgcn_mfma_i32_16x16x64_i8(
                     *(const v4i*)(Ab + (4 * wvt + 3) * 64), bcf3, Dc, 0, 0, 0);
            *(v4i*)(redC_t + wvt * 1024 + L * 16) = Dc;
        }
        __syncthreads();
        if (wvt == 0 && col < NCLS) {
            v4i c0 = *(const v4i*)(redC_t + 0 * 1024 + L * 16);
#pragma unroll
            for (int jj = 1; jj < 4; ++jj) {
                const v4i cj = *(const v4i*)(redC_t + jj * 1024 + L * 16);
#pragma unroll
                for (int r = 0; r < 4; ++r) c0[r] += cj[r];
            }
#pragma unroll
            for (int r = 0; r < 4; ++r) {
                const float vcn = ALPHA * vc[r] + cscale * (float)c0[r];
                const int sc = (vcn >= THRESH);
                out[(size_t)(g * 16 + rowq * 4 + r) * NCLS + col] = (float)(accc[r] + sc);
            }
        }
    }
    {
#pragma unroll
        for (int r = 0; r < 4; ++r) {
            const int bglob = g * 16 + rowq * 4 + r;
            out[BATCH * NCLS + (size_t)bglob * NRES + nn] = (float)accv[r];
        }
    }
}

extern "C" void kernel_launch(void* const* d_in, const int* in_sizes, int n_in,
                              void* d_out, int out_size, void* d_ws, size_t ws_size,
                              hipStream_t stream) {
    (void)in_sizes; (void)n_in; (void)out_size; (void)ws_size;
    const float* x     = (const float*)d_in[0];
    const float* W_in  = (const float*)d_in[1];
    const float* W_res = (const float*)d_in[2];
    const float* W_clf = (const float*)d_in[3];
    float* out = (float*)d_out;
    unsigned char* ws = (unsigned char*)d_ws;

    // zero: scale slots + rowmax + ENTIRE tagged-mask region (tags 0 never match)
    hipMemsetAsync(ws, 0, MASK_OFF + 262144, stream);
    rowmax_kernel<<<256, 256, 0, stream>>>(W_res, (float*)(ws + ROWMAX_OFF));
    maxabs_kernel<<<16, 256, 0, stream>>>(W_clf, NCLS * NRES, (unsigned*)(ws + SLOTC_OFF));
    quant_res<<<1024, 256, 0, stream>>>(W_res, (const float*)(ws + ROWMAX_OFF),
                                        (unsigned*)(ws + WQF_OFF));
    quant_clf<<<16, 256, 0, stream>>>(W_clf, (const unsigned*)(ws + SLOTC_OFF),
                                      (unsigned*)(ws + WCF_OFF));
    reservoir_mfma<<<NPAIR * NSLICE, 512, LDS_BYTES, stream>>>(x, W_in, ws, out);
}

// Round 5
// 6856.055 us; speedup vs baseline: 1.8488x; 1.8488x over previous
//
#include <hip/hip_runtime.h>

#define ALPHA 0.9f
#define THRESH 1.0f
#define BATCH 512
#define CIN 16
#define TSTEPS 2000
#define NRES 1024
#define NCLS 10

#define NGROUP 32       // 32 batch groups of 16 rows
#define BPG 8           // blocks per group, 128 neurons each

typedef int   v4i __attribute__((ext_vector_type(4)));
typedef float v4f __attribute__((ext_vector_type(4)));
typedef short v8s __attribute__((ext_vector_type(8)));

// ---- ws layout (bytes) ---- (identical to the verified 5.14 ms kernel)
#define SLOTC_OFF  8192     // max|W_clf| bits
#define ROWMAX_OFF 9216     // per-row max|W_res[n][:]|, 1024 floats
#define MASK_OFF   16384    // tagged masks: 2 par x 32 g x 16 b x 64 prod x 4 B = 256 KB
#define WQF_OFF    278528   // W_res int8, MFMA-fragment order: 1 MB
#define WCF_OFF    1327104  // W_clf int8 fragment tile: 16 KB
// LDS: B slice + A + xA (parity-double-buffered) + redC
#define LDS_BYTES  (131072 + 16*1040 + 2048 + 8192)

__global__ __launch_bounds__(256) void maxabs_kernel(const float* __restrict__ W,
                                                     int n, unsigned* __restrict__ slot) {
    unsigned m = 0u;
    for (int i = blockIdx.x * 256 + threadIdx.x; i < n; i += gridDim.x * 256)
        m = max(m, __float_as_uint(W[i]) & 0x7fffffffu);
#pragma unroll
    for (int off = 32; off >= 1; off >>= 1)
        m = max(m, (unsigned)__shfl_xor((int)m, off, 64));
    if ((threadIdx.x & 63) == 0) atomicMax(slot, m);
}

// per-row max|W_res[n][:]| — one wave per row, plain store (deterministic)
__global__ __launch_bounds__(256) void rowmax_kernel(const float* __restrict__ W,
                                                     float* __restrict__ rowmax) {
    const int row = blockIdx.x * 4 + ((int)threadIdx.x >> 6);
    const int lane = threadIdx.x & 63;
    float m = 0.f;
    for (int j = lane; j < NRES; j += 64) m = fmaxf(m, fabsf(W[row * NRES + j]));
#pragma unroll
    for (int off = 32; off >= 1; off >>= 1) m = fmaxf(m, __shfl_xor(m, off, 64));
    if (lane == 0) rowmax[row] = m;
}

// W_res -> signed-int8 (PER-ROW scale) in MFMA B-fragment order:
// dword o4: bl=o4>>15, wv=(o4>>12)&7, kt=(o4>>8)&15, L=(o4>>2)&63, i0=(o4&3)*4
// n = bl*128+wv*16+(L&15); k = kt*64+(L>>4)*16+i0..+3
__global__ __launch_bounds__(256) void quant_res(const float* __restrict__ W,
                                                 const float* __restrict__ rowmax,
                                                 unsigned* __restrict__ dst) {
    const int o4 = blockIdx.x * 256 + threadIdx.x;
    const int bl = o4 >> 15, wv = (o4 >> 12) & 7, kt = (o4 >> 8) & 15;
    const int L = (o4 >> 2) & 63, i0 = (o4 & 3) * 4;
    const int n = bl * 128 + wv * 16 + (L & 15);
    const int k = kt * 64 + (L >> 4) * 16 + i0;
    const float inv = 127.0f / rowmax[n];
    unsigned dw = 0;
#pragma unroll
    for (int j = 0; j < 4; ++j) {
        float q = rintf(W[n * NRES + k + j] * inv);
        q = fminf(fmaxf(q, -127.f), 127.f);
        dw |= ((unsigned)((int)q & 0xff)) << (8 * j);
    }
    dst[o4] = dw;
}

// W_clf -> int8 fragment tile (16 cols, cls>=10 zero): 4096 dwords
__global__ __launch_bounds__(256) void quant_clf(const float* __restrict__ W,
                                                 const unsigned* __restrict__ slot,
                                                 unsigned* __restrict__ dst) {
    const int o4 = blockIdx.x * 256 + threadIdx.x;
    const int kt = (o4 >> 8) & 15, L = (o4 >> 2) & 63, i0 = (o4 & 3) * 4;
    const int cls = L & 15;
    const int k = kt * 64 + (L >> 4) * 16 + i0;
    const float inv = 127.0f / __uint_as_float(*slot);
    unsigned dw = 0;
    if (cls < NCLS) {
#pragma unroll
        for (int j = 0; j < 4; ++j) {
            float q = rintf(W[cls * NRES + k + j] * inv);
            q = fminf(fmaxf(q, -127.f), 127.f);
            dw |= ((unsigned)((int)q & 0xff)) << (8 * j);
        }
    }
    dst[o4] = dw;
}

__device__ __forceinline__ unsigned short f2bf(float f) {
    unsigned u = __float_as_uint(f);
    return (unsigned short)((u + 0x7fffu + ((u >> 16) & 1u)) >> 16);
}

// LDS-only barrier: orders LDS ops (lgkmcnt) + rendezvous, WITHOUT the
// vmcnt(0) drain __syncthreads emits. The agent-scope publish stores and x
// prefetch loads stay in flight across it (tags self-validate; loads are
// waited at their use). sched_barrier + "memory" clobbers pin LDS ops.
__device__ __forceinline__ void bar_lds() {
    asm volatile("s_waitcnt lgkmcnt(0)" ::: "memory");
    __builtin_amdgcn_sched_barrier(0);
    __builtin_amdgcn_s_barrier();
    __builtin_amdgcn_sched_barrier(0);
    asm volatile("" ::: "memory");
}

// ---------------------------------------------------------------------------
// 256 blocks x 512 threads (1/CU). Block = (group g, slot bl): 16 batch rows
// x 128 neurons, int8 W slice LDS-resident. Mask transport identical to the
// verified 5.14 ms kernel. Changes (all serialization-stripping, numerics
// bit-identical):
//  (1) in-loop barriers are raw s_barrier + lgkmcnt only (no vmcnt drain);
//  (2) publish hoisted to right after each wave's last A-read -> producer
//      time is per-wave, not max-over-block+barrier;
//  (3) S3 removed for non-clf blocks (poll-gating covers the A/xA WAR
//      hazards: a consumer's poll succeeds only after ALL 64 producer waves
//      published, and each publishes after its Din/Drec reads);
//  (4) x prefetched one step ahead into a register; xA double-buffered by
//      step parity so staging precedes the poll.
// ---------------------------------------------------------------------------
__global__ __launch_bounds__(512, 1) void reservoir_mfma(
    const float* __restrict__ x, const float* __restrict__ W_in,
    unsigned char* __restrict__ ws, float* __restrict__ out)
{
    // XCD co-location: 8 blocks of a group share q%8 (dispatch heuristic).
    const int q   = (int)blockIdx.x;
    const int g   = (q & 7) * 4 + ((q >> 3) & 3);
    const int bl  = q >> 5;
    const int tid = (int)threadIdx.x;
    const int L    = tid & 63;
    const int wv   = tid >> 6;     // 0..7
    const int col  = L & 15;       // MFMA n-col (neuron/cls)
    const int rowq = L >> 4;       // batch quad

    extern __shared__ char lds[];
    char* B_lds = lds;                                   // 131072 B
    char* A_lds = lds + 131072;                          // 16 x 1040 B
    unsigned short* xA = (unsigned short*)(lds + 131072 + 16 * 1040);  // 2 x 16x32 bf16
    char* redC = lds + 131072 + 16 * 1040 + 2048;        // 8 KB clf partials

    const float* rowmax = (const float*)(ws + ROWMAX_OFF);
    const float cscale = __uint_as_float(*(const unsigned*)(ws + SLOTC_OFF)) * (1.0f / 127.0f);
    unsigned char* maskbuf = ws + MASK_OFF;
    const unsigned char* wqf = ws + WQF_OFF;
    const unsigned char* wcf = ws + WCF_OFF;

    const int nn = bl * 128 + wv * 16 + col;             // my output neuron
    const float dscale = rowmax[nn] * (1.0f / 127.0f);
    const bool clfBlk = (bl == 0);

    // ---- load my 128 KB weight slice into LDS
    {
        const v4i* src = (const v4i*)(wqf + (size_t)bl * 131072);
        v4i* dst = (v4i*)B_lds;
        for (int i = tid; i < 8192; i += 512) dst[i] = src[i];
    }

    // ---- W_in hi/lo bf16 B-fragments
    v8s binf_h, binf_l;
#pragma unroll
    for (int i = 0; i < 8; ++i) {
        const int c = (rowq * 8 + i) & 15;
        const float w = W_in[nn * CIN + c];
        const unsigned short h = f2bf(w);
        const float wl = w - __uint_as_float((unsigned)h << 16);
        binf_h[i] = (short)h;
        binf_l[i] = (short)f2bf(wl);
    }

    // ---- classifier fragments preloaded to registers (block 0: wave wv owns kt=2wv,2wv+1)
    v4i bcf0 = {0,0,0,0}, bcf1 = {0,0,0,0};
    if (clfBlk) {
        bcf0 = *(const v4i*)(wcf + (2 * wv + 0) * 1024 + L * 16);
        bcf1 = *(const v4i*)(wcf + (2 * wv + 1) * 1024 + L * 16);
    }

    float v[4]  = {0.f, 0.f, 0.f, 0.f};
    int   accv[4] = {0, 0, 0, 0};
    float vc[4] = {0.f, 0.f, 0.f, 0.f};   // live on block0/wave0
    int   accc[4] = {0, 0, 0, 0};

    const int mb = tid >> 5, mseg = tid & 31;   // my mask-poll / A-build slot
    const unsigned long long* mybase0 = (const unsigned long long*)(maskbuf +
        (size_t)((0 * NGROUP + g) * 16 + mb) * 256 + mseg * 8);
    const unsigned long long* mybase1 = (const unsigned long long*)(maskbuf +
        (size_t)((1 * NGROUP + g) * 16 + mb) * 256 + mseg * 8);

    // x element (tid<256): prefetched one step ahead into a register
    const int xb = (tid >> 4) & 15, xc = tid & 15;
    const size_t xoff = ((size_t)(g * 16 + xb) * CIN + xc) * TSTEPS;
    float xval = (tid < 256) ? x[xoff] : 0.f;

    __syncthreads();

    for (int t = 0; t < TSTEPS; ++t) {
        // ---- stage x_t hi/lo into parity buffer (before the poll; safe:
        //      writes buf[t&1], Din(t-1) read buf[(t-1)&1]; older reuse of
        //      buf[t&1] (Din(t-2)) is ordered by the S2 barrier of step t-1)
        if (tid < 256) {
            unsigned short* xr = xA + (t & 1) * 512;
            const unsigned short h = f2bf(xval);
            const float lo2 = xval - __uint_as_float((unsigned)h << 16);
            xr[xb * 32 + xc] = h;
            xr[xb * 32 + 16 + xc] = f2bf(lo2);
        }

        if (t > 0) {
            // ---- poll tagged masks of step t-1 (parity (t-1)&1), expand to A
            const unsigned long long* mp = ((t - 1) & 1) ? mybase1 : mybase0;
            const unsigned want = (unsigned)t;
            unsigned lo, hi;
            for (;;) {
                const unsigned long long u =
                    __hip_atomic_load(mp, __ATOMIC_RELAXED, __HIP_MEMORY_SCOPE_AGENT);
                lo = (unsigned)u; hi = (unsigned)(u >> 32);
                if (((lo >> 16) == want) & ((hi >> 16) == want)) break;
                __builtin_amdgcn_s_sleep(1);
            }
            const unsigned m = (lo & 0xffffu) | ((hi & 0xffffu) << 16);
            unsigned w[8];
#pragma unroll
            for (int d = 0; d < 8; ++d) {
                const unsigned mm = m >> (4 * d);
                w[d] = (mm & 1u) | ((mm & 2u) << 7) | ((mm & 4u) << 14) | ((mm & 8u) << 21);
            }
            v4i* dst = (v4i*)(A_lds + mb * 1040 + mseg * 32);
            dst[0] = *(v4i*)&w[0];
            dst[1] = *(v4i*)&w[4];
        }
        bar_lds();   // S2: A + xA ready (LDS-only drain; publish/x stay in flight)

        // ---- prefetch next step's x under the MFMA phase
        float xnext = 0.f;
        if (tid < 256 && t + 1 < TSTEPS) xnext = x[xoff + (t + 1)];

        // ---- input projection: (xh+xl).(Wh+Wl), 2 chained bf16 MFMAs
        v4f Din;
        {
            const v8s xa = *(const v8s*)((const char*)(xA + (t & 1) * 512)
                                         + col * 64 + rowq * 16);
            v4f z = {0.f, 0.f, 0.f, 0.f};
            const v4f D1 = __builtin_amdgcn_mfma_f32_16x16x32_bf16(xa, binf_h, z, 0, 0, 0);
            Din = __builtin_amdgcn_mfma_f32_16x16x32_bf16(xa, binf_l, D1, 0, 0, 0);
        }

        // ---- recurrent: 16 x mfma_i32_16x16x64_i8, 2 independent chains (exact)
        v4i Drec = {0, 0, 0, 0};
        if (t > 0) {
            const char* Bb = B_lds + wv * 16384;
            const char* Ab = A_lds + col * 1040 + rowq * 16;
            v4i Dr0 = {0,0,0,0}, Dr1 = {0,0,0,0};
#pragma unroll 4
            for (int kt = 0; kt < 16; kt += 2) {
                const v4i a0 = *(const v4i*)(Ab + kt * 64);
                const v4i b0 = *(const v4i*)(Bb + kt * 1024 + L * 16);
                const v4i a1 = *(const v4i*)(Ab + (kt + 1) * 64);
                const v4i b1 = *(const v4i*)(Bb + (kt + 1) * 1024 + L * 16);
                Dr0 = __builtin_amdgcn_mfma_i32_16x16x64_i8(a0, b0, Dr0, 0, 0, 0);
                Dr1 = __builtin_amdgcn_mfma_i32_16x16x64_i8(a1, b1, Dr1, 0, 0, 0);
            }
#pragma unroll
            for (int r = 0; r < 4; ++r) Drec[r] = Dr0[r] + Dr1[r];
        }

        // ---- LIF + spikes + ballots
        unsigned long long bal0, bal1, bal2, bal3;
        {
            float vn; int s;
            vn = ALPHA * v[0] + Din[0] + dscale * (float)Drec[0];
            s = (vn >= THRESH); accv[0] += s; v[0] = s ? 0.f : vn; bal0 = __ballot(s);
            vn = ALPHA * v[1] + Din[1] + dscale * (float)Drec[1];
            s = (vn >= THRESH); accv[1] += s; v[1] = s ? 0.f : vn; bal1 = __ballot(s);
            vn = ALPHA * v[2] + Din[2] + dscale * (float)Drec[2];
            s = (vn >= THRESH); accv[2] += s; v[2] = s ? 0.f : vn; bal2 = __ballot(s);
            vn = ALPHA * v[3] + Din[3] + dscale * (float)Drec[3];
            s = (vn >= THRESH); accv[3] += s; v[3] = s ? 0.f : vn; bal3 = __ballot(s);
        }

        // ---- classifier partials (block 0, BEFORE publish: they read A, and
        //      the publish must remain the block's last A-read per the
        //      poll-gating invariant)
        if (clfBlk && t > 0) {
            const char* Ab = A_lds + col * 1040 + rowq * 16;
            v4i Dc = {0, 0, 0, 0};
            const v4i a0 = *(const v4i*)(Ab + (2 * wv + 0) * 64);
            const v4i a1 = *(const v4i*)(Ab + (2 * wv + 1) * 64);
            Dc = __builtin_amdgcn_mfma_i32_16x16x64_i8(a0, bcf0, Dc, 0, 0, 0);
            Dc = __builtin_amdgcn_mfma_i32_16x16x64_i8(a1, bcf1, Dc, 0, 0, 0);
            *(v4i*)(redC + wv * 1024 + L * 16) = Dc;
        }

        // ---- publish tagged mask dword (tag = t+1), lanes 0..15 — per-wave,
        //      immediately after this wave's last A-read; no barrier first
        {
            const int p = t & 1;
            if (L < 16) {
                const int b = L;
                const unsigned long long bb = (b & 2) ? ((b & 1) ? bal3 : bal2)
                                                      : ((b & 1) ? bal1 : bal0);
                const unsigned fld = (unsigned)((bb >> ((b >> 2) * 16)) & 0xFFFFu);
                unsigned* mp = (unsigned*)(maskbuf +
                    (size_t)((p * NGROUP + g) * 16 + b) * 256 + (bl * 8 + wv) * 4);
                __hip_atomic_store(mp, ((unsigned)(t + 1) << 16) | fld,
                                   __ATOMIC_RELAXED, __HIP_MEMORY_SCOPE_AGENT);
            }
        }

        // ---- clf blocks only: redC handoff barrier + wave-0 reduce
        if (clfBlk) {
            bar_lds();   // S3 (clf only): redC ready
            if (wv == 0 && t > 0) {
                v4i c0 = *(const v4i*)(redC + 0 * 1024 + L * 16);
#pragma unroll
                for (int jj = 1; jj < 8; ++jj) {
                    const v4i cj = *(const v4i*)(redC + jj * 1024 + L * 16);
#pragma unroll
                    for (int r = 0; r < 4; ++r) c0[r] += cj[r];
                }
#pragma unroll
                for (int r = 0; r < 4; ++r) {
                    const float vcn = ALPHA * vc[r] + cscale * (float)c0[r];
                    const int sc = (vcn >= THRESH);
                    accc[r] += sc;
                    vc[r] = sc ? 0.f : vcn;
                }
            }
        }
        xval = xnext;
        // no end-of-loop barrier: each thread's next-step poll gates its own
        // A-build write (all 64 producer waves published => all finished
        // their Din/Drec/clf A-reads); xA is parity-protected.
    }

    // ---- epilogue: classifier flush with s_{T-1} (parity 1, tag TSTEPS)
    if (clfBlk) {
        {
            const unsigned want = (unsigned)TSTEPS;
            unsigned lo, hi;
            for (;;) {
                const unsigned long long u =
                    __hip_atomic_load(mybase1, __ATOMIC_RELAXED, __HIP_MEMORY_SCOPE_AGENT);
                lo = (unsigned)u; hi = (unsigned)(u >> 32);
                if (((lo >> 16) == want) & ((hi >> 16) == want)) break;
                __builtin_amdgcn_s_sleep(1);
            }
            const unsigned m = (lo & 0xffffu) | ((hi & 0xffffu) << 16);
            unsigned w[8];
#pragma unroll
            for (int d = 0; d < 8; ++d) {
                const unsigned mm = m >> (4 * d);
                w[d] = (mm & 1u) | ((mm & 2u) << 7) | ((mm & 4u) << 14) | ((mm & 8u) << 21);
            }
            v4i* dst = (v4i*)(A_lds + mb * 1040 + mseg * 32);
            dst[0] = *(v4i*)&w[0];
            dst[1] = *(v4i*)&w[4];
        }
        __syncthreads();
        {
            const char* Ab = A_lds + col * 1040 + rowq * 16;
            v4i Dc = {0, 0, 0, 0};
            const v4i a0 = *(const v4i*)(Ab + (2 * wv + 0) * 64);
            const v4i a1 = *(const v4i*)(Ab + (2 * wv + 1) * 64);
            Dc = __builtin_amdgcn_mfma_i32_16x16x64_i8(a0, bcf0, Dc, 0, 0, 0);
            Dc = __builtin_amdgcn_mfma_i32_16x16x64_i8(a1, bcf1, Dc, 0, 0, 0);
            *(v4i*)(redC + wv * 1024 + L * 16) = Dc;
        }
        __syncthreads();
        if (wv == 0 && col < NCLS) {
            v4i c0 = *(const v4i*)(redC + 0 * 1024 + L * 16);
#pragma unroll
            for (int jj = 1; jj < 8; ++jj) {
                const v4i cj = *(const v4i*)(redC + jj * 1024 + L * 16);
#pragma unroll
                for (int r = 0; r < 4; ++r) c0[r] += cj[r];
            }
#pragma unroll
            for (int r = 0; r < 4; ++r) {
                const float vcn = ALPHA * vc[r] + cscale * (float)c0[r];
                const int sc = (vcn >= THRESH);
                out[(size_t)(g * 16 + rowq * 4 + r) * NCLS + col] = (float)(accc[r] + sc);
            }
        }
    }
    {
#pragma unroll
        for (int r = 0; r < 4; ++r) {
            const int bglob = g * 16 + rowq * 4 + r;
            out[BATCH * NCLS + (size_t)bglob * NRES + nn] = (float)accv[r];
        }
    }
}

extern "C" void kernel_launch(void* const* d_in, const int* in_sizes, int n_in,
                              void* d_out, int out_size, void* d_ws, size_t ws_size,
                              hipStream_t stream) {
    (void)in_sizes; (void)n_in; (void)out_size; (void)ws_size;
    const float* x     = (const float*)d_in[0];
    const float* W_in  = (const float*)d_in[1];
    const float* W_res = (const float*)d_in[2];
    const float* W_clf = (const float*)d_in[3];
    float* out = (float*)d_out;
    unsigned char* ws = (unsigned char*)d_ws;

    // zero: scale slots + rowmax + ENTIRE tagged-mask region (tags 0 never match)
    hipMemsetAsync(ws, 0, MASK_OFF + 262144, stream);
    rowmax_kernel<<<256, 256, 0, stream>>>(W_res, (float*)(ws + ROWMAX_OFF));
    maxabs_kernel<<<16, 256, 0, stream>>>(W_clf, NCLS * NRES, (unsigned*)(ws + SLOTC_OFF));
    quant_res<<<1024, 256, 0, stream>>>(W_res, (const float*)(ws + ROWMAX_OFF),
                                        (unsigned*)(ws + WQF_OFF));
    quant_clf<<<16, 256, 0, stream>>>(W_clf, (const unsigned*)(ws + SLOTC_OFF),
                                      (unsigned*)(ws + WCF_OFF));
    reservoir_mfma<<<NGROUP * BPG, 512, LDS_BYTES, stream>>>(x, W_in, ws, out);
}

// Round 6
// 3483.001 us; speedup vs baseline: 3.6393x; 1.9684x over previous
//
#include <hip/hip_runtime.h>

#define ALPHA 0.9f
#define THRESH 1.0f
#define BATCH 512
#define CIN 16
#define TSTEPS 2000
#define NRES 1024
#define NCLS 10

#define NGROUP 32       // 32 batch groups of 16 rows
#define BPG 8           // blocks per group, 128 neurons each

typedef int   v4i __attribute__((ext_vector_type(4)));
typedef float v4f __attribute__((ext_vector_type(4)));
typedef short v8s __attribute__((ext_vector_type(8)));

// ---- ws layout (bytes) ----
#define SLOTC_OFF  8192     // max|W_clf| bits
#define ROWMAX_OFF 9216     // per-row max|W_res[n][:]|, 1024 floats
// tagged masks, PRODUCER-MAJOR: 2 par x 32 g x 64 producer x 16 row x 4 B = 256 KB
// (wave publish = lanes 0..15 -> ONE contiguous 64B line at P*64)
#define MASK_OFF   16384
#define WQF_OFF    278528   // W_res int8, MFMA-fragment order: 1 MB
#define WCF_OFF    1327104  // W_clf int8 fragment tile: 16 KB
#define LDS_BYTES  (131072 + 16*1040 + 1024 + 8192)  // B slice + A + xA + redC

__global__ __launch_bounds__(256) void maxabs_kernel(const float* __restrict__ W,
                                                     int n, unsigned* __restrict__ slot) {
    unsigned m = 0u;
    for (int i = blockIdx.x * 256 + threadIdx.x; i < n; i += gridDim.x * 256)
        m = max(m, __float_as_uint(W[i]) & 0x7fffffffu);
#pragma unroll
    for (int off = 32; off >= 1; off >>= 1)
        m = max(m, (unsigned)__shfl_xor((int)m, off, 64));
    if ((threadIdx.x & 63) == 0) atomicMax(slot, m);
}

// per-row max|W_res[n][:]| — one wave per row, plain store (deterministic)
__global__ __launch_bounds__(256) void rowmax_kernel(const float* __restrict__ W,
                                                     float* __restrict__ rowmax) {
    const int row = blockIdx.x * 4 + ((int)threadIdx.x >> 6);
    const int lane = threadIdx.x & 63;
    float m = 0.f;
    for (int j = lane; j < NRES; j += 64) m = fmaxf(m, fabsf(W[row * NRES + j]));
#pragma unroll
    for (int off = 32; off >= 1; off >>= 1) m = fmaxf(m, __shfl_xor(m, off, 64));
    if (lane == 0) rowmax[row] = m;
}

// W_res -> signed-int8 (PER-ROW scale) in MFMA B-fragment order:
// dword o4: bl=o4>>15, wv=(o4>>12)&7, kt=(o4>>8)&15, L=(o4>>2)&63, i0=(o4&3)*4
// n = bl*128+wv*16+(L&15); k = kt*64+(L>>4)*16+i0..+3
__global__ __launch_bounds__(256) void quant_res(const float* __restrict__ W,
                                                 const float* __restrict__ rowmax,
                                                 unsigned* __restrict__ dst) {
    const int o4 = blockIdx.x * 256 + threadIdx.x;
    const int bl = o4 >> 15, wv = (o4 >> 12) & 7, kt = (o4 >> 8) & 15;
    const int L = (o4 >> 2) & 63, i0 = (o4 & 3) * 4;
    const int n = bl * 128 + wv * 16 + (L & 15);
    const int k = kt * 64 + (L >> 4) * 16 + i0;
    const float inv = 127.0f / rowmax[n];
    unsigned dw = 0;
#pragma unroll
    for (int j = 0; j < 4; ++j) {
        float q = rintf(W[n * NRES + k + j] * inv);
        q = fminf(fmaxf(q, -127.f), 127.f);
        dw |= ((unsigned)((int)q & 0xff)) << (8 * j);
    }
    dst[o4] = dw;
}

// W_clf -> int8 fragment tile (16 cols, cls>=10 zero): 4096 dwords
__global__ __launch_bounds__(256) void quant_clf(const float* __restrict__ W,
                                                 const unsigned* __restrict__ slot,
                                                 unsigned* __restrict__ dst) {
    const int o4 = blockIdx.x * 256 + threadIdx.x;
    const int kt = (o4 >> 8) & 15, L = (o4 >> 2) & 63, i0 = (o4 & 3) * 4;
    const int cls = L & 15;
    const int k = kt * 64 + (L >> 4) * 16 + i0;
    const float inv = 127.0f / __uint_as_float(*slot);
    unsigned dw = 0;
    if (cls < NCLS) {
#pragma unroll
        for (int j = 0; j < 4; ++j) {
            float q = rintf(W[cls * NRES + k + j] * inv);
            q = fminf(fmaxf(q, -127.f), 127.f);
            dw |= ((unsigned)((int)q & 0xff)) << (8 * j);
        }
    }
    dst[o4] = dw;
}

__device__ __forceinline__ unsigned short f2bf(float f) {
    unsigned u = __float_as_uint(f);
    return (unsigned short)((u + 0x7fffu + ((u >> 16) & 1u)) >> 16);
}

// 16 spike bits -> 16 int8 {0,1} bytes (carry-free nibble spread:
// x*0x00204081 places bits at 0/8/16/24; shifts never overlap for x<16)
__device__ __forceinline__ v4i expand16(unsigned m16) {
    unsigned w[4];
#pragma unroll
    for (int d = 0; d < 4; ++d)
        w[d] = (((m16 >> (4 * d)) & 15u) * 0x00204081u) & 0x01010101u;
    return *(v4i*)&w[0];
}

// ---------------------------------------------------------------------------
// 256 blocks x 512 threads (1/CU). Block = (group g, slot bl): 16 batch rows
// x 128 neurons, int8 W slice LDS-resident. Identical to the verified 5.14 ms
// kernel EXCEPT:
//  (1) mask buffer is PRODUCER-MAJOR: producer P=bl*8+wv owns one 64B line
//      (16 rows x 4B). A wave's publish (lanes 0..15) is ONE contiguous
//      full-line write-through instead of 16 scattered partial-line commits
//      -> 16x less write-line traffic, faster visibility at the coherence
//      point. Consumers poll (P=tt>>3, rowpair k=tt&7) with one dwordx2 and
//      expand rows 2k/2k+1 into the SAME A-fragment addresses as before.
//  (2) publish hoisted above clf-partial/S3 (depends only on ballots; S3
//      still orders all iteration-crossing LDS hazards).
// Numerics bit-identical (absmax must be exactly 32).
// ---------------------------------------------------------------------------
__global__ __launch_bounds__(512, 1) void reservoir_mfma(
    const float* __restrict__ x, const float* __restrict__ W_in,
    unsigned char* __restrict__ ws, float* __restrict__ out)
{
    // XCD co-location: 8 blocks of a group share q%8 (dispatch heuristic).
    const int q   = (int)blockIdx.x;
    const int g   = (q & 7) * 4 + ((q >> 3) & 3);
    const int bl  = q >> 5;
    const int tid = (int)threadIdx.x;
    const int L    = tid & 63;
    const int wv   = tid >> 6;     // 0..7
    const int col  = L & 15;       // MFMA n-col (neuron/cls)
    const int rowq = L >> 4;       // batch quad

    extern __shared__ char lds[];
    char* B_lds = lds;                                   // 131072 B
    char* A_lds = lds + 131072;                          // 16 x 1040 B
    unsigned short* xA = (unsigned short*)(lds + 131072 + 16 * 1040);  // 16x32 bf16
    char* redC = lds + 131072 + 16 * 1040 + 1024;        // 8 KB clf partials

    const float* rowmax = (const float*)(ws + ROWMAX_OFF);
    const float cscale = __uint_as_float(*(const unsigned*)(ws + SLOTC_OFF)) * (1.0f / 127.0f);
    unsigned char* maskbuf = ws + MASK_OFF;
    const unsigned char* wqf = ws + WQF_OFF;
    const unsigned char* wcf = ws + WCF_OFF;

    const int nn = bl * 128 + wv * 16 + col;             // my output neuron
    const float dscale = rowmax[nn] * (1.0f / 127.0f);
    const bool clfBlk = (bl == 0);

    // ---- load my 128 KB weight slice into LDS
    {
        const v4i* src = (const v4i*)(wqf + (size_t)bl * 131072);
        v4i* dst = (v4i*)B_lds;
        for (int i = tid; i < 8192; i += 512) dst[i] = src[i];
    }

    // ---- W_in hi/lo bf16 B-fragments
    v8s binf_h, binf_l;
#pragma unroll
    for (int i = 0; i < 8; ++i) {
        const int c = (rowq * 8 + i) & 15;
        const float w = W_in[nn * CIN + c];
        const unsigned short h = f2bf(w);
        const float wl = w - __uint_as_float((unsigned)h << 16);
        binf_h[i] = (short)h;
        binf_l[i] = (short)f2bf(wl);
    }

    // ---- classifier fragments preloaded to registers (block 0: wave wv owns kt=2wv,2wv+1)
    v4i bcf0 = {0,0,0,0}, bcf1 = {0,0,0,0};
    if (clfBlk) {
        bcf0 = *(const v4i*)(wcf + (2 * wv + 0) * 1024 + L * 16);
        bcf1 = *(const v4i*)(wcf + (2 * wv + 1) * 1024 + L * 16);
    }

    float v[4]  = {0.f, 0.f, 0.f, 0.f};
    int   accv[4] = {0, 0, 0, 0};
    float vc[4] = {0.f, 0.f, 0.f, 0.f};   // live on block0/wave0
    int   accc[4] = {0, 0, 0, 0};

    // mask poll (producer-major): thread tt polls producer P=tt>>3, rows 2k/2k+1
    const int pP = tid >> 3, pk = tid & 7;
    const unsigned long long* mybase0 = (const unsigned long long*)(maskbuf +
        (size_t)(0 * NGROUP + g) * 4096 + pP * 64 + pk * 8);
    const unsigned long long* mybase1 = (const unsigned long long*)(maskbuf +
        (size_t)(1 * NGROUP + g) * 4096 + pP * 64 + pk * 8);

    __syncthreads();

    for (int t = 0; t < TSTEPS; ++t) {
        // x_t load issued before the poll
        float xval = 0.f;
        if (tid < 256) {
            const int b = tid >> 4, c = tid & 15;
            xval = x[((size_t)(g * 16 + b) * CIN + c) * TSTEPS + t];
        }

        if (t > 0) {
            // ---- poll tagged masks of step t-1 (parity (t-1)&1), expand to A
            const unsigned long long* mp = ((t - 1) & 1) ? mybase1 : mybase0;
            const unsigned want = (unsigned)t;
            unsigned lo, hi;
            for (;;) {
                const unsigned long long u =
                    __hip_atomic_load(mp, __ATOMIC_RELAXED, __HIP_MEMORY_SCOPE_AGENT);
                lo = (unsigned)u; hi = (unsigned)(u >> 32);
                if (((lo >> 16) == want) & ((hi >> 16) == want)) break;
                __builtin_amdgcn_s_sleep(1);
            }
            // rows 2k (lo) and 2k+1 (hi) of producer P -> A[row][16P..16P+15]
            *(v4i*)(A_lds + (2 * pk + 0) * 1040 + pP * 16) = expand16(lo & 0xffffu);
            *(v4i*)(A_lds + (2 * pk + 1) * 1040 + pP * 16) = expand16(hi & 0xffffu);
        }
        // ---- stage x_t hi/lo
        if (tid < 256) {
            const int b = tid >> 4, c = tid & 15;
            const unsigned short h = f2bf(xval);
            const float lo2 = xval - __uint_as_float((unsigned)h << 16);
            xA[b * 32 + c] = h;
            xA[b * 32 + 16 + c] = f2bf(lo2);
        }
        __syncthreads();   // S2: A + xA ready

        // ---- input projection: (xh+xl).(Wh+Wl), 2 chained bf16 MFMAs
        v4f Din;
        {
            const v8s xa = *(const v8s*)((const char*)xA + col * 64 + rowq * 16);
            v4f z = {0.f, 0.f, 0.f, 0.f};
            const v4f D1 = __builtin_amdgcn_mfma_f32_16x16x32_bf16(xa, binf_h, z, 0, 0, 0);
            Din = __builtin_amdgcn_mfma_f32_16x16x32_bf16(xa, binf_l, D1, 0, 0, 0);
        }

        // ---- recurrent: 16 x mfma_i32_16x16x64_i8, 2 independent chains (exact)
        v4i Drec = {0, 0, 0, 0};
        if (t > 0) {
            const char* Bb = B_lds + wv * 16384;
            const char* Ab = A_lds + col * 1040 + rowq * 16;
            v4i Dr0 = {0,0,0,0}, Dr1 = {0,0,0,0};
#pragma unroll 4
            for (int kt = 0; kt < 16; kt += 2) {
                const v4i a0 = *(const v4i*)(Ab + kt * 64);
                const v4i b0 = *(const v4i*)(Bb + kt * 1024 + L * 16);
                const v4i a1 = *(const v4i*)(Ab + (kt + 1) * 64);
                const v4i b1 = *(const v4i*)(Bb + (kt + 1) * 1024 + L * 16);
                Dr0 = __builtin_amdgcn_mfma_i32_16x16x64_i8(a0, b0, Dr0, 0, 0, 0);
                Dr1 = __builtin_amdgcn_mfma_i32_16x16x64_i8(a1, b1, Dr1, 0, 0, 0);
            }
#pragma unroll
            for (int r = 0; r < 4; ++r) Drec[r] = Dr0[r] + Dr1[r];
        }

        // ---- LIF + spikes + ballots (register-only; moved before clf/S3)
        unsigned long long bal0, bal1, bal2, bal3;
        {
            float vn; int s;
            vn = ALPHA * v[0] + Din[0] + dscale * (float)Drec[0];
            s = (vn >= THRESH); accv[0] += s; v[0] = s ? 0.f : vn; bal0 = __ballot(s);
            vn = ALPHA * v[1] + Din[1] + dscale * (float)Drec[1];
            s = (vn >= THRESH); accv[1] += s; v[1] = s ? 0.f : vn; bal1 = __ballot(s);
            vn = ALPHA * v[2] + Din[2] + dscale * (float)Drec[2];
            s = (vn >= THRESH); accv[2] += s; v[2] = s ? 0.f : vn; bal2 = __ballot(s);
            vn = ALPHA * v[3] + Din[3] + dscale * (float)Drec[3];
            s = (vn >= THRESH); accv[3] += s; v[3] = s ? 0.f : vn; bal3 = __ballot(s);
        }

        // ---- publish tagged masks (tag = t+1): lanes 0..15 write ONE
        //      contiguous 64B line at producer slot P=bl*8+wv
        {
            const int p = t & 1;
            if (L < 16) {
                const int b = L;
                const unsigned long long bb = (b & 2) ? ((b & 1) ? bal3 : bal2)
                                                      : ((b & 1) ? bal1 : bal0);
                const unsigned fld = (unsigned)((bb >> ((b >> 2) * 16)) & 0xFFFFu);
                unsigned* mp = (unsigned*)(maskbuf +
                    (size_t)(p * NGROUP + g) * 4096 + (bl * 8 + wv) * 64 + b * 4);
                __hip_atomic_store(mp, ((unsigned)(t + 1) << 16) | fld,
                                   __ATOMIC_RELAXED, __HIP_MEMORY_SCOPE_AGENT);
            }
        }

        // ---- classifier partials (block 0, spread: wave wv does kt=2wv,2wv+1)
        if (clfBlk && t > 0) {
            const char* Ab = A_lds + col * 1040 + rowq * 16;
            v4i Dc = {0, 0, 0, 0};
            const v4i a0 = *(const v4i*)(Ab + (2 * wv + 0) * 64);
            const v4i a1 = *(const v4i*)(Ab + (2 * wv + 1) * 64);
            Dc = __builtin_amdgcn_mfma_i32_16x16x64_i8(a0, bcf0, Dc, 0, 0, 0);
            Dc = __builtin_amdgcn_mfma_i32_16x16x64_i8(a1, bcf1, Dc, 0, 0, 0);
            *(v4i*)(redC + wv * 1024 + L * 16) = Dc;
        }
        __syncthreads();   // S3: A consumed; redC ready

        // ---- classifier reduce + LIF (block 0, wave 0; reads redC after S3)
        if (clfBlk && wv == 0 && t > 0) {
            v4i c0 = *(const v4i*)(redC + 0 * 1024 + L * 16);
#pragma unroll
            for (int jj = 1; jj < 8; ++jj) {
                const v4i cj = *(const v4i*)(redC + jj * 1024 + L * 16);
#pragma unroll
                for (int r = 0; r < 4; ++r) c0[r] += cj[r];
            }
#pragma unroll
            for (int r = 0; r < 4; ++r) {
                const float vcn = ALPHA * vc[r] + cscale * (float)c0[r];
                const int sc = (vcn >= THRESH);
                accc[r] += sc;
                vc[r] = sc ? 0.f : vcn;
            }
        }
        // no end-of-loop barrier: S3 separates this step's A/xA reads from the
        // next step's poll-gated A/xA writes.
    }

    // ---- epilogue: classifier flush with s_{T-1} (parity 1, tag TSTEPS)
    if (clfBlk) {
        {
            const unsigned want = (unsigned)TSTEPS;
            unsigned lo, hi;
            for (;;) {
                const unsigned long long u =
                    __hip_atomic_load(mybase1, __ATOMIC_RELAXED, __HIP_MEMORY_SCOPE_AGENT);
                lo = (unsigned)u; hi = (unsigned)(u >> 32);
                if (((lo >> 16) == want) & ((hi >> 16) == want)) break;
                __builtin_amdgcn_s_sleep(1);
            }
            *(v4i*)(A_lds + (2 * pk + 0) * 1040 + pP * 16) = expand16(lo & 0xffffu);
            *(v4i*)(A_lds + (2 * pk + 1) * 1040 + pP * 16) = expand16(hi & 0xffffu);
        }
        __syncthreads();
        {
            const char* Ab = A_lds + col * 1040 + rowq * 16;
            v4i Dc = {0, 0, 0, 0};
            const v4i a0 = *(const v4i*)(Ab + (2 * wv + 0) * 64);
            const v4i a1 = *(const v4i*)(Ab + (2 * wv + 1) * 64);
            Dc = __builtin_amdgcn_mfma_i32_16x16x64_i8(a0, bcf0, Dc, 0, 0, 0);
            Dc = __builtin_amdgcn_mfma_i32_16x16x64_i8(a1, bcf1, Dc, 0, 0, 0);
            *(v4i*)(redC + wv * 1024 + L * 16) = Dc;
        }
        __syncthreads();
        if (wv == 0 && col < NCLS) {
            v4i c0 = *(const v4i*)(redC + 0 * 1024 + L * 16);
#pragma unroll
            for (int jj = 1; jj < 8; ++jj) {
                const v4i cj = *(const v4i*)(redC + jj * 1024 + L * 16);
#pragma unroll
                for (int r = 0; r < 4; ++r) c0[r] += cj[r];
            }
#pragma unroll
            for (int r = 0; r < 4; ++r) {
                const float vcn = ALPHA * vc[r] + cscale * (float)c0[r];
                const int sc = (vcn >= THRESH);
                out[(size_t)(g * 16 + rowq * 4 + r) * NCLS + col] = (float)(accc[r] + sc);
            }
        }
    }
    {
#pragma unroll
        for (int r = 0; r < 4; ++r) {
            const int bglob = g * 16 + rowq * 4 + r;
            out[BATCH * NCLS + (size_t)bglob * NRES + nn] = (float)accv[r];
        }
    }
}

extern "C" void kernel_launch(void* const* d_in, const int* in_sizes, int n_in,
                              void* d_out, int out_size, void* d_ws, size_t ws_size,
                              hipStream_t stream) {
    (void)in_sizes; (void)n_in; (void)out_size; (void)ws_size;
    const float* x     = (const float*)d_in[0];
    const float* W_in  = (const float*)d_in[1];
    const float* W_res = (const float*)d_in[2];
    const float* W_clf = (const float*)d_in[3];
    float* out = (float*)d_out;
    unsigned char* ws = (unsigned char*)d_ws;

    // zero: scale slots + rowmax + ENTIRE tagged-mask region (tags 0 never match)
    hipMemsetAsync(ws, 0, MASK_OFF + 262144, stream);
    rowmax_kernel<<<256, 256, 0, stream>>>(W_res, (float*)(ws + ROWMAX_OFF));
    maxabs_kernel<<<16, 256, 0, stream>>>(W_clf, NCLS * NRES, (unsigned*)(ws + SLOTC_OFF));
    quant_res<<<1024, 256, 0, stream>>>(W_res, (const float*)(ws + ROWMAX_OFF),
                                        (unsigned*)(ws + WQF_OFF));
    quant_clf<<<16, 256, 0, stream>>>(W_clf, (const unsigned*)(ws + SLOTC_OFF),
                                      (unsigned*)(ws + WCF_OFF));
    reservoir_mfma<<<NGROUP * BPG, 512, LDS_BYTES, stream>>>(x, W_in, ws, out);
}